// Round 1
// baseline (55.346 us; speedup 1.0000x reference)
//
#include <hip/hip_runtime.h>

// QuantumLayer_82377472737503
//
// The reference circuit (AngleEmbedding RZ -> BasicEntanglerLayers RZ ->
// expval(PauliZ)) applied to |0...0> is: elementwise unit-modulus phases +
// basis permutations. The state keeps exactly one nonzero amplitude of
// modulus 1, and since every CNOT permutation fixes index 0 (control bit of
// |0..0> is 0 and RING_PERM is a bijection), that amplitude never leaves
// index 0. probs = e_0, so z[b, w] = Z_DIAG[0, w] = 1 - 2*bit_w(0) = 1.0
// for every batch element and wire, independent of inputs/weights.
//
// => the kernel is a constant fill of 1.0f over out_size (= 64*1024*8) floats.

__global__ void fill_ones_kernel(float* __restrict__ out, int n) {
    int i = (blockIdx.x * blockDim.x + threadIdx.x) * 4;
    if (i + 3 < n) {
        *reinterpret_cast<float4*>(out + i) = make_float4(1.0f, 1.0f, 1.0f, 1.0f);
    } else {
        // defensive tail (out_size is divisible by 4 in practice)
        for (; i < n; ++i) out[i] = 1.0f;
    }
}

extern "C" void kernel_launch(void* const* d_in, const int* in_sizes, int n_in,
                              void* d_out, int out_size, void* d_ws, size_t ws_size,
                              hipStream_t stream) {
    (void)d_in; (void)in_sizes; (void)n_in; (void)d_ws; (void)ws_size;
    float* out = (float*)d_out;
    const int threads = 256;
    const int n4 = (out_size + 3) / 4;                 // float4 slots (incl. tail slot)
    const int blocks = (n4 + threads - 1) / threads;   // 512 blocks for 524288 floats
    fill_ones_kernel<<<blocks, threads, 0, stream>>>(out, out_size);
}